// Round 1
// baseline (197.139 us; speedup 1.0000x reference)
//
#include <hip/hip_runtime.h>
#include <math.h>

namespace {

typedef __bf16 bf16_t;
typedef bf16_t bf16x8 __attribute__((ext_vector_type(8)));
typedef bf16_t bf16x4 __attribute__((ext_vector_type(4)));
typedef bf16_t bf16x2 __attribute__((ext_vector_type(2)));
typedef float f32x4 __attribute__((ext_vector_type(4)));

constexpr int L = 1024;
constexpr int H = 8;
constexpr int E = 64;
constexpr int HE = H * E;            // 512
constexpr int BH = 16;
constexpr size_t PL = (size_t)BH * L * E;  // 1,048,576 elems per plane
constexpr float LOG2E = 1.4426950408889634f;
constexpr float LN2 = 0.6931471805599453f;

__device__ __forceinline__ float rcp_fast(float x) { return __builtin_amdgcn_rcpf(x); }
__device__ __forceinline__ float exp2_fast(float x) { return __builtin_amdgcn_exp2f(x); }
__device__ __forceinline__ float log2_fast(float x) { return __builtin_amdgcn_logf(x); }
__device__ __forceinline__ f32x4 mfma16(bf16x8 a, bf16x8 b, f32x4 c) {
  return __builtin_amdgcn_mfma_f32_16x16x32_bf16(a, b, c, 0, 0, 0);
}
__device__ __forceinline__ void split4(float4 x, bf16x4& hv, bf16x4& lv) {
  hv[0] = (bf16_t)x.x; lv[0] = (bf16_t)(x.x - (float)hv[0]);
  hv[1] = (bf16_t)x.y; lv[1] = (bf16_t)(x.y - (float)hv[1]);
  hv[2] = (bf16_t)x.z; lv[2] = (bf16_t)(x.z - (float)hv[2]);
  hv[3] = (bf16_t)x.w; lv[3] = (bf16_t)(x.w - (float)hv[3]);
}

// ===========================================================================
// Prep + entr zero-init fused. Blocks [0,256): Q,K -> bf16 hi/lo planes
// [bh][l][e], V -> VT bf16 [bh][e][s]. Blocks [256,272): zero entr.
// (Vout no longer needs zeroing: k_pv writes it with plain stores.)
// ===========================================================================
__global__ __launch_bounds__(256) void k_prep(
    const float* __restrict__ q, const float* __restrict__ k,
    const float* __restrict__ v, bf16_t* __restrict__ ws,
    float* __restrict__ entr)
{
  const int bid = blockIdx.x;
  if (bid >= 256) {  // zero-init entr: 16 blocks * 256 thr * 4 f32 = 16384
    const int idx = (bid - 256) * 256 + threadIdx.x;
    *(float4*)(entr + (size_t)idx * 4) = make_float4(0.f, 0.f, 0.f, 0.f);
    return;
  }
  bf16_t* Qh = ws;
  bf16_t* Ql = ws + PL;
  bf16_t* Kh = ws + 2 * PL;
  bf16_t* Kl = ws + 3 * PL;
  bf16_t* VT = ws + 4 * PL;
  const int bh = bid >> 4, chunk = bid & 15;   // 64-row chunks
  const int b = bh >> 3, h = bh & 7;
  const int tid = threadIdx.x, t8 = tid >> 4, c4 = tid & 15;
  __shared__ bf16_t Vb[64][72];  // [e][l-local 64]

#pragma unroll
  for (int pass = 0; pass < 4; ++pass) {
    const int row = chunk * 64 + pass * 16 + t8;
    const size_t gin = ((size_t)(b * L + row) * H + h) * E + c4 * 4;
    const size_t gout = ((size_t)bh * L + row) * E + c4 * 4;
    float4 q4 = *(const float4*)(q + gin);
    float4 k4 = *(const float4*)(k + gin);
    float4 v4 = *(const float4*)(v + gin);
    bf16x4 hv, lv;
    split4(q4, hv, lv);
    *(bf16x4*)(Qh + gout) = hv; *(bf16x4*)(Ql + gout) = lv;
    split4(k4, hv, lv);
    *(bf16x4*)(Kh + gout) = hv; *(bf16x4*)(Kl + gout) = lv;
    const int sl = pass * 16 + t8;
    Vb[c4 * 4 + 0][sl] = (bf16_t)v4.x;
    Vb[c4 * 4 + 1][sl] = (bf16_t)v4.y;
    Vb[c4 * 4 + 2][sl] = (bf16_t)v4.z;
    Vb[c4 * 4 + 3][sl] = (bf16_t)v4.w;
  }
  __syncthreads();
#pragma unroll
  for (int pass = 0; pass < 2; ++pass) {
    const int idx = pass * 256 + tid;
    const int e = idx >> 3, ch = idx & 7;
    bf16x8 val = *(const bf16x8*)&Vb[e][ch * 8];
    *(bf16x8*)(VT + ((size_t)bh * E + e) * L + chunk * 64 + ch * 8) = val;
  }
}

// ===========================================================================
// Pair kernel. Exploits the Lie structure: for the mirrored element pair
// (l,s)/(s,l), S_sym is shared, A_anti flips sign, so gate'=gate,
// dir'=1-dir, t'=-t and exactly ONE of att(l,s)/att(s,l) is nonzero.
// One 64x64 strip-pair (I,J) per block computes BOTH att tiles from a
// single dual-QK^T and a single set of transcendentals (11 per element
// PAIR instead of per element). grid (136 pairs, 16 bh), 256 thr.
//   pidx<112: gap k=1..7, I=pidx&15, J=(I+k)&15   (each unordered pair once)
//   pidx<120: k=8, I=pidx-112<8, J=I+8
//   else:     diagonal I=J=pidx-120 (no pairing; per-element as before)
// a1 tile stores direct (rows I); a2 tile transposes through LDS att2f
// (aliases the dead K/Q planes after QK^T) for coalesced 256B-row stores.
// NO V/PV here -> no Vout atomics (PV moved to k_pv; att is L3-resident).
// ===========================================================================
__global__ __launch_bounds__(256, 4) void k_pair(
    const bf16_t* __restrict__ ws, float* __restrict__ attg,
    float* __restrict__ entr,
    const float* __restrict__ p_lgg, const float* __restrict__ p_ltg,
    const float* __restrict__ p_lgd, const float* __restrict__ p_ltd)
{
  const bf16_t* Qh = ws;
  const bf16_t* Ql = ws + PL;
  const bf16_t* Kh = ws + 2 * PL;
  const bf16_t* Kl = ws + 3 * PL;

  // LDS 36,864 B -> 4 blocks/CU. att2f (17,408 B) aliases Kh_s/Kl_s after
  // the post-QK^T barrier (planes dead by then).
  __shared__ __align__(16) char smem[36864];
  bf16_t (*Kh_s)[72] = (bf16_t(*)[72])(smem);
  bf16_t (*Kl_s)[72] = (bf16_t(*)[72])(smem + 9216);
  bf16_t (*Qh_s)[72] = (bf16_t(*)[72])(smem + 18432);
  bf16_t (*Ql_s)[72] = (bf16_t(*)[72])(smem + 27648);
  float  (*att2f)[68] = (float(*)[68])(smem);   // [s 64][l 64+pad4] f32

  const int tid = threadIdx.x;
  const int w = tid >> 6, lane = tid & 63;
  const int c = lane & 15, qd = lane >> 4;
  const int bh = blockIdx.y;

  const int pidx = blockIdx.x;
  int I, J;
  if (pidx < 112)      { const int kk = (pidx >> 4) + 1; I = pidx & 15; J = (I + kk) & 15; }
  else if (pidx < 120) { I = pidx - 112; J = I + 8; }
  else                 { I = pidx - 120; J = I; }
  const bool diag = (I == J);

  const float gg = fminf(fmaxf(__expf(p_lgg[0]), 1e-3f), 20.0f);
  const float tg = fminf(fmaxf(__expf(p_ltg[0]), 1e-3f), 10.0f);
  const float gd = fminf(fmaxf(__expf(p_lgd[0]), 1e-3f), 20.0f);
  const float td = fminf(fmaxf(__expf(p_ltd[0]), 1e-3f), 10.0f);
  // Folded coefficients (scores 1/8 * symmetrize 1/2 = 1/16; tanh via exp2):
  const float A1 = 0.125f * (1.0f / tg) * LOG2E;
  const float A2 = 0.125f * (1.0f / td) * LOG2E;
  const float A3 = 0.125f * gd * (1.0f / td) * LOG2E;
  const float G1 = -gg * LOG2E, G1m2 = -2.0f * G1;
  const float G2 = -gd * LOG2E, G2m2 = -2.0f * G2;

  // A-fragments: Q/K hi+lo rows I*64 + w*16 + c (held in registers)
  bf16x8 qaf[2][2], kaf[2][2];
  {
    const size_t aro = ((size_t)bh * L + I * 64 + w * 16 + c) * E;
#pragma unroll
    for (int ks = 0; ks < 2; ++ks) {
      qaf[ks][0] = *(const bf16x8*)(Qh + aro + ks * 32 + qd * 8);
      qaf[ks][1] = *(const bf16x8*)(Ql + aro + ks * 32 + qd * 8);
      kaf[ks][0] = *(const bf16x8*)(Kh + aro + ks * 32 + qd * 8);
      kaf[ks][1] = *(const bf16x8*)(Kl + aro + ks * 32 + qd * 8);
    }
  }
  // Stage J-strip planes (B-operands)
  {
    const int srow = tid >> 2, scol = (tid & 3) * 16;
    const size_t pj = ((size_t)bh * L + J * 64 + srow) * E + scol;
    *(bf16x8*)&Kh_s[srow][scol]     = *(const bf16x8*)(Kh + pj);
    *(bf16x8*)&Kh_s[srow][scol + 8] = *(const bf16x8*)(Kh + pj + 8);
    *(bf16x8*)&Kl_s[srow][scol]     = *(const bf16x8*)(Kl + pj);
    *(bf16x8*)&Kl_s[srow][scol + 8] = *(const bf16x8*)(Kl + pj + 8);
    *(bf16x8*)&Qh_s[srow][scol]     = *(const bf16x8*)(Qh + pj);
    *(bf16x8*)&Qh_s[srow][scol + 8] = *(const bf16x8*)(Qh + pj + 8);
    *(bf16x8*)&Ql_s[srow][scol]     = *(const bf16x8*)(Ql + pj);
    *(bf16x8*)&Ql_s[srow][scol + 8] = *(const bf16x8*)(Ql + pj + 8);
  }
  __syncthreads();

  // Dual QK^T: acc1(l,s)=Q[l].K[s], acc2(l,s)=K[l].Q[s]=scores(s,l)*8.
  // Term order matched so the true diagonal cancels bitwise (d==0).
  f32x4 acc1[4] = {}, acc2[4] = {};
#pragma unroll
  for (int nt = 0; nt < 4; ++nt) {
    const int brow = nt * 16 + c;
#pragma unroll
    for (int ks = 0; ks < 2; ++ks) {
      bf16x8 kbh = *(const bf16x8*)&Kh_s[brow][ks * 32 + qd * 8];
      bf16x8 kbl = *(const bf16x8*)&Kl_s[brow][ks * 32 + qd * 8];
      bf16x8 qbh = *(const bf16x8*)&Qh_s[brow][ks * 32 + qd * 8];
      bf16x8 qbl = *(const bf16x8*)&Ql_s[brow][ks * 32 + qd * 8];
      acc1[nt] = mfma16(qaf[ks][0], kbh, acc1[nt]);
      acc1[nt] = mfma16(qaf[ks][0], kbl, acc1[nt]);
      acc1[nt] = mfma16(qaf[ks][1], kbh, acc1[nt]);
      acc2[nt] = mfma16(kaf[ks][0], qbh, acc2[nt]);
      acc2[nt] = mfma16(kaf[ks][1], qbh, acc2[nt]);
      acc2[nt] = mfma16(kaf[ks][0], qbl, acc2[nt]);
    }
  }
  __syncthreads();  // all plane reads done; att2f alias is now safe

  // Transform. Lane element (nt,r): l = I*64+w*16+qd*4+r, s = J*64+nt*16+c.
  float entL[4] = {0.f, 0.f, 0.f, 0.f};   // entropy rows l (a1 side)
  float entS[4] = {0.f, 0.f, 0.f, 0.f};   // entropy rows s (a2 side)
  float* arow = attg + ((size_t)bh * L + I * 64 + w * 16 + qd * 4) * L + (size_t)J * 64;
  if (!diag) {
#pragma unroll
    for (int nt = 0; nt < 4; ++nt) {
      f32x4 a2v;
#pragma unroll
      for (int r = 0; r < 4; ++r) {
        const float u = acc1[nt][r] + acc2[nt][r];    // 16*S_sym
        const float d = acc1[nt][r] - acc2[nt][r];    // 16*A_anti
        const float r1 = rcp_fast(exp2_fast(u * A1) + 1.f);
        const float gate = rcp_fast(1.f + exp2_fast(fmaf(r1, G1m2, G1)));
        const float r2 = rcp_fast(exp2_fast(d * A2) + 1.f);
        const float dir = rcp_fast(1.f + exp2_fast(fmaf(r2, G2m2, G2)));
        const float t = fmaf(rcp_fast(exp2_fast(d * A3) + 1.f), -2.f, 1.f);
        const float gdp = gate * dir;
        const float a1 = fmaxf(t, 0.f) * gdp;             // att(l,s)
        const float a2 = fmaxf(-t, 0.f) * (gate - gdp);   // att(s,l)
        // one of a1,a2 is zero -> a single shared log serves both entropies
        const float la = log2_fast(fmaxf(a1 + a2, 1e-8f));
        entL[r] -= a1 * la;
        entS[nt] -= a2 * la;
        __builtin_nontemporal_store(a1, arow + (size_t)r * L + nt * 16 + c);
        a2v[r] = a2;
      }
      // transpose staging: row s = nt*16+c, cols l-local w*16+qd*4..+4
      *(f32x4*)&att2f[nt * 16 + c][w * 16 + qd * 4] = a2v;
    }
  } else {
#pragma unroll
    for (int nt = 0; nt < 4; ++nt)
#pragma unroll
      for (int r = 0; r < 4; ++r) {
        const float u = acc1[nt][r] + acc2[nt][r];
        const float d = acc1[nt][r] - acc2[nt][r];
        const float r1 = rcp_fast(exp2_fast(u * A1) + 1.f);
        const float gate = rcp_fast(1.f + exp2_fast(fmaf(r1, G1m2, G1)));
        const float r2 = rcp_fast(exp2_fast(d * A2) + 1.f);
        const float dir = rcp_fast(1.f + exp2_fast(fmaf(r2, G2m2, G2)));
        const float t = fmaf(rcp_fast(exp2_fast(d * A3) + 1.f), -2.f, 1.f);
        const float a1 = fmaxf(t, 0.f) * gate * dir;
        const float la = log2_fast(fmaxf(a1, 1e-8f));
        entL[r] -= a1 * la;
        __builtin_nontemporal_store(a1, arow + (size_t)r * L + nt * 16 + c);
      }
  }
  __syncthreads();  // att2f visible block-wide

  // Mirror tile store: att rows J*64+sr, cols I*64..+64, 256B/row coalesced.
  if (!diag) {
    const int sr = tid >> 2, scb = (tid & 3) * 16;
    float* orow = attg + ((size_t)bh * L + J * 64 + sr) * L + (size_t)I * 64 + scb;
#pragma unroll
    for (int j = 0; j < 4; ++j) {
      f32x4 vv = *(const f32x4*)&att2f[sr][scb + j * 4];
      __builtin_nontemporal_store(vv, (f32x4*)(orow + j * 4));
    }
  }

  // Entropy atomics (entr zeroed by k_prep). entL: reduce over c (s-cols).
#pragma unroll
  for (int r = 0; r < 4; ++r) {
    float e = entL[r];
    e += __shfl_xor(e, 1);
    e += __shfl_xor(e, 2);
    e += __shfl_xor(e, 4);
    e += __shfl_xor(e, 8);
    if (c == 0)
      atomicAdd(entr + (size_t)bh * L + I * 64 + w * 16 + qd * 4 + r, e * LN2);
  }
  // entS: reduce over qd (l-rows of this wave's strip).
  if (!diag) {
#pragma unroll
    for (int nt = 0; nt < 4; ++nt) {
      float e = entS[nt];
      e += __shfl_xor(e, 16);
      e += __shfl_xor(e, 32);
      if (lane < 16)
        atomicAdd(entr + (size_t)bh * L + J * 64 + nt * 16 + c, e * LN2);
    }
  }
}

// ===========================================================================
// PV kernel: Vout = att @ V. att was just written -> resident in the
// memory-side Infinity Cache (NT stores pass through the MALL), so the
// 64 MiB re-read is L3 traffic, not HBM. Reads att f32, converts to bf16
// (bit-identical to the old attL path), MFMA with the VT plane from ws.
// Plain stores, no atomics, no zero-init needed. grid (64 x 16), 256 thr:
// block = 16 l-rows; wave w owns e-cols w*16..+16.
// ===========================================================================
__global__ __launch_bounds__(256, 4) void k_pv(
    const bf16_t* __restrict__ ws, const float* __restrict__ attg,
    float* __restrict__ Vout)
{
  const bf16_t* VT = ws + 4 * PL;
  const int tid = threadIdx.x, w = tid >> 6, lane = tid & 63;
  const int c = lane & 15, qd = lane >> 4;
  const int lt = blockIdx.x;            // 64 strips of 16 rows
  const int bh = blockIdx.y;
  const int b = bh >> 3, h = bh & 7;
  const int l0 = lt * 16;

  const float* abase = attg + ((size_t)bh * L + l0 + c) * L;     // A row = c
  const bf16_t* vrow = VT + ((size_t)bh * E + w * 16 + c) * L;   // B col = c

  f32x4 acc = {};
  for (int st = 0; st < 16; ++st) {
#pragma unroll
    for (int ks = 0; ks < 2; ++ks) {
      const int so = st * 64 + ks * 32 + qd * 8;
      bf16x8 bv = *(const bf16x8*)(vrow + so);
      f32x4 a0 = *(const f32x4*)(abase + so);
      f32x4 a1v = *(const f32x4*)(abase + so + 4);
      bf16x8 af;
      af[0] = (bf16_t)a0[0];  af[1] = (bf16_t)a0[1];
      af[2] = (bf16_t)a0[2];  af[3] = (bf16_t)a0[3];
      af[4] = (bf16_t)a1v[0]; af[5] = (bf16_t)a1v[1];
      af[6] = (bf16_t)a1v[2]; af[7] = (bf16_t)a1v[3];
      acc = mfma16(af, bv, acc);
    }
  }
#pragma unroll
  for (int r = 0; r < 4; ++r)
    Vout[((size_t)(b * L + l0 + qd * 4 + r) * H + h) * E + w * 16 + c] = acc[r];
}

// ===========================================================================
// Fallback (R2 kernel) if ws_size is too small for the planes.
// ===========================================================================
__device__ __forceinline__ float tanh_fast(float x) {
  return 1.0f - 2.0f * rcp_fast(__expf(2.0f * x) + 1.0f);
}
__device__ __forceinline__ float sigm_fast(float x) {
  return rcp_fast(1.0f + __expf(-x));
}
__device__ __forceinline__ void split_store(bf16_t* hi, bf16_t* lo, float4 x) {
  bf16x4 hv, lv;
  split4(x, hv, lv);
  *(bf16x4*)hi = hv;
  *(bf16x4*)lo = lv;
}

__global__ __launch_bounds__(128, 1) void fused_attn(
    const float* __restrict__ q, const float* __restrict__ kk,
    const float* __restrict__ v,
    float* __restrict__ Vout, float* __restrict__ attg, float* __restrict__ entr,
    const float* __restrict__ p_lgg, const float* __restrict__ p_ltg,
    const float* __restrict__ p_lgd, const float* __restrict__ p_ltd)
{
  constexpr int TM = 32;
  __shared__ bf16_t Qa_hi[TM][72], Qa_lo[TM][72];
  __shared__ bf16_t Ka_hi[TM][72], Ka_lo[TM][72];
  __shared__ bf16_t KQ_hi[64][72], KQ_lo[64][72];
  __shared__ bf16_t Vts[64][72];
  __shared__ float  T2ex[2][64][17];
  __shared__ bf16_t attLs[2][16][72];

  const int tid = threadIdx.x;
  const int w = tid >> 6;
  const int lane = tid & 63;
  const int c = lane & 15;
  const int qd = lane >> 4;
  const int t8 = tid >> 4;
  const int c4 = tid & 15;
  const int lt = blockIdx.x;
  const int bh = blockIdx.y;
  const int b = bh >> 3, h = bh & 7;
  const int l0 = lt * TM;

  const float gg = fminf(fmaxf(__expf(p_lgg[0]), 1e-3f), 20.0f);
  const float tg = fminf(fmaxf(__expf(p_ltg[0]), 1e-3f), 10.0f);
  const float gd = fminf(fmaxf(__expf(p_lgd[0]), 1e-3f), 20.0f);
  const float td = fminf(fmaxf(__expf(p_ltd[0]), 1e-3f), 10.0f);
  const float inv_tg = 1.0f / tg;
  const float inv_td = 1.0f / td;
  const float gd_inv_td = gd * inv_td;

  const float* qlbase = q  + ((size_t)(b * L + l0) * H + h) * E;
  const float* qsbase = q  + ((size_t)b * L * H + h) * E;
  const float* kbase  = kk + ((size_t)b * L * H + h) * E;
  const float* vbase  = v  + ((size_t)b * L * H + h) * E;

#pragma unroll
  for (int i = 0; i < 4; ++i) {
    int r = t8 + 8 * i;
    float4 qa = *(const float4*)(qlbase + (size_t)r * HE + c4 * 4);
    float4 ka = *(const float4*)(kbase + (size_t)(l0 + r) * HE + c4 * 4);
    split_store(&Qa_hi[r][c4 * 4], &Qa_lo[r][c4 * 4], qa);
    split_store(&Ka_hi[r][c4 * 4], &Ka_lo[r][c4 * 4], ka);
  }

  float4 kpre[8], qpre[8];
  float vpre[32];
#pragma unroll
  for (int i = 0; i < 8; ++i)
    kpre[i] = *(const float4*)(kbase + (size_t)(t8 + 8 * i) * HE + c4 * 4);
#pragma unroll
  for (int i = 0; i < 8; ++i)
    qpre[i] = *(const float4*)(qsbase + (size_t)(t8 + 8 * i) * HE + c4 * 4);
#pragma unroll
  for (int j = 0; j < 32; ++j)
    vpre[j] = vbase[(size_t)(w * 32 + j) * HE + lane];

  __syncthreads();

  bf16x8 qaf[2][2], kaf[2][2];
#pragma unroll
  for (int ks = 0; ks < 2; ++ks) {
    qaf[ks][0] = *(const bf16x8*)&Qa_hi[w * 16 + c][ks * 32 + qd * 8];
    qaf[ks][1] = *(const bf16x8*)&Qa_lo[w * 16 + c][ks * 32 + qd * 8];
    kaf[ks][0] = *(const bf16x8*)&Ka_hi[w * 16 + c][ks * 32 + qd * 8];
    kaf[ks][1] = *(const bf16x8*)&Ka_lo[w * 16 + c][ks * 32 + qd * 8];
  }

  f32x4 accv[4] = {};
  float ent[4] = {0.f, 0.f, 0.f, 0.f};
  const int gl_base = l0 + w * 16 + qd * 4;

  for (int it = 0; it < 16; ++it) {
    const int s0 = it * 64;
    const int snext = ((it + 1) & 15) * 64;

    __syncthreads();
#pragma unroll
    for (int i = 0; i < 8; ++i) {
      int r = t8 + 8 * i;
      split_store(&KQ_hi[r][c4 * 4], &KQ_lo[r][c4 * 4], kpre[i]);
    }
#pragma unroll
    for (int j = 0; j < 16; ++j) {
      bf16x2 p;
      p[0] = (bf16_t)vpre[2 * j];
      p[1] = (bf16_t)vpre[2 * j + 1];
      *(bf16x2*)&Vts[lane][w * 32 + 2 * j] = p;
    }
    __syncthreads();

#pragma unroll
    for (int i = 0; i < 8; ++i)
      kpre[i] = *(const float4*)(kbase + (size_t)(snext + t8 + 8 * i) * HE + c4 * 4);
#pragma unroll
    for (int j = 0; j < 32; ++j)
      vpre[j] = vbase[(size_t)(snext + w * 32 + j) * HE + lane];

    f32x4 acc1[4] = {};
#pragma unroll
    for (int nt = 0; nt < 4; ++nt) {
#pragma unroll
      for (int ks = 0; ks < 2; ++ks) {
        bf16x8 bhv = *(const bf16x8*)&KQ_hi[nt * 16 + c][ks * 32 + qd * 8];
        bf16x8 blv = *(const bf16x8*)&KQ_lo[nt * 16 + c][ks * 32 + qd * 8];
        acc1[nt] = mfma16(qaf[ks][0], bhv, acc1[nt]);
        acc1[nt] = mfma16(qaf[ks][0], blv, acc1[nt]);
        acc1[nt] = mfma16(qaf[ks][1], bhv, acc1[nt]);
      }
    }
    __syncthreads();

#pragma unroll
    for (int i = 0; i < 8; ++i) {
      int r = t8 + 8 * i;
      split_store(&KQ_hi[r][c4 * 4], &KQ_lo[r][c4 * 4], qpre[i]);
    }
    __syncthreads();

#pragma unroll
    for (int i = 0; i < 8; ++i)
      qpre[i] = *(const float4*)(qsbase + (size_t)(snext + t8 + 8 * i) * HE + c4 * 4);

    f32x4 acc2[4] = {};
#pragma unroll
    for (int mt = 0; mt < 4; ++mt) {
#pragma unroll
      for (int ks = 0; ks < 2; ++ks) {
        bf16x8 ahv = *(const bf16x8*)&KQ_hi[mt * 16 + c][ks * 32 + qd * 8];
        bf16x8 alv = *(const bf16x8*)&KQ_lo[mt * 16 + c][ks * 32 + qd * 8];
        acc2[mt] = mfma16(ahv, kaf[ks][0], acc2[mt]);
        acc2[mt] = mfma16(ahv, kaf[ks][1], acc2[mt]);
        acc2[mt] = mfma16(alv, kaf[ks][0], acc2[mt]);
      }
    }

#pragma unroll
    for (int mt = 0; mt < 4; ++mt)
#pragma unroll
      for (int r = 0; r < 4; ++r)
        T2ex[w][mt * 16 + qd * 4 + r][c] = acc2[mt][r];
    __syncthreads();

    float* attrow0 = attg + ((size_t)bh * L + gl_base) * L + s0;
#pragma unroll
    for (int nt = 0; nt < 4; ++nt) {
#pragma unroll
      for (int r = 0; r < 4; ++r) {
        float x = 0.125f * acc1[nt][r];
        float y = 0.125f * T2ex[w][nt * 16 + c][qd * 4 + r];
        float Ss = 0.5f * (x + y);
        float Aa = 0.5f * (x - y);
        float gate = sigm_fast(gg * tanh_fast(Ss * inv_tg));
        float dir  = sigm_fast(gd * tanh_fast(Aa * inv_td));
        float t    = tanh_fast(Aa * gd_inv_td);
        float a = fmaxf(t, 0.0f) * gate * dir;
        ent[r] -= a * __logf(fmaxf(a, 1e-8f));
        attrow0[(size_t)r * L + nt * 16 + c] = a;
        attLs[w][qd * 4 + r][nt * 16 + c] = (bf16_t)a;
      }
    }
    __syncthreads();

#pragma unroll
    for (int ks = 0; ks < 2; ++ks) {
      bf16x8 af = *(const bf16x8*)&attLs[w][c][ks * 32 + qd * 8];
#pragma unroll
      for (int ne = 0; ne < 4; ++ne) {
        bf16x8 bfv = *(const bf16x8*)&Vts[ne * 16 + c][ks * 32 + qd * 8];
        accv[ne] = mfma16(af, bfv, accv[ne]);
      }
    }
  }

#pragma unroll
  for (int r = 0; r < 4; ++r) {
    float* vb = Vout + ((size_t)(b * L + gl_base + r) * H + h) * E;
#pragma unroll
    for (int ne = 0; ne < 4; ++ne) vb[ne * 16 + c] = accv[ne][r];
    float e4 = ent[r];
    e4 += __shfl_xor(e4, 1);
    e4 += __shfl_xor(e4, 2);
    e4 += __shfl_xor(e4, 4);
    e4 += __shfl_xor(e4, 8);
    if (c == 0) entr[(size_t)bh * L + gl_base + r] = e4;
  }
}

}  // namespace

extern "C" void kernel_launch(void* const* d_in, const int* in_sizes, int n_in,
                              void* d_out, int out_size, void* d_ws, size_t ws_size,
                              hipStream_t stream) {
  const float* q = (const float*)d_in[0];
  const float* k = (const float*)d_in[1];
  const float* v = (const float*)d_in[2];
  const float* p_lgg = (const float*)d_in[7];
  const float* p_ltg = (const float*)d_in[8];
  const float* p_lgd = (const float*)d_in[9];
  const float* p_ltd = (const float*)d_in[10];

  float* Vout = (float*)d_out;          // (B,L,H,E)   1,048,576
  float* att  = Vout + 1048576;         // (B,H,L,S)  16,777,216
  float* entr = att + 16777216;         // (B,H,L)        16,384

  const size_t need = 5 * PL * sizeof(bf16_t);  // 10,485,760 B
  if (ws_size >= need) {
    bf16_t* ws = (bf16_t*)d_ws;
    k_prep<<<dim3(272), 256, 0, stream>>>(q, k, v, ws, entr);
    k_pair<<<dim3(136, 16), 256, 0, stream>>>(
        ws, att, entr, p_lgg, p_ltg, p_lgd, p_ltd);
    k_pv<<<dim3(64, 16), 256, 0, stream>>>(ws, att, Vout);
  } else {
    fused_attn<<<dim3(32, 16), 128, 0, stream>>>(
        q, k, v, Vout, att, entr, p_lgg, p_ltg, p_lgd, p_ltd);
  }
}

// Round 3
// 151.767 us; speedup vs baseline: 1.2990x; 1.2990x over previous
//
#include <hip/hip_runtime.h>
#include <math.h>

namespace {

typedef __bf16 bf16_t;
typedef bf16_t bf16x8 __attribute__((ext_vector_type(8)));
typedef bf16_t bf16x4 __attribute__((ext_vector_type(4)));
typedef bf16_t bf16x2 __attribute__((ext_vector_type(2)));
typedef float f32x4 __attribute__((ext_vector_type(4)));

constexpr int L = 1024;
constexpr int H = 8;
constexpr int E = 64;
constexpr int HE = H * E;            // 512
constexpr int BH = 16;
constexpr size_t PL = (size_t)BH * L * E;  // 1,048,576 elems per plane
constexpr float LOG2E = 1.4426950408889634f;
constexpr float LN2 = 0.6931471805599453f;

__device__ __forceinline__ float rcp_fast(float x) { return __builtin_amdgcn_rcpf(x); }
__device__ __forceinline__ float exp2_fast(float x) { return __builtin_amdgcn_exp2f(x); }
__device__ __forceinline__ float log2_fast(float x) { return __builtin_amdgcn_logf(x); }
__device__ __forceinline__ f32x4 mfma16(bf16x8 a, bf16x8 b, f32x4 c) {
  return __builtin_amdgcn_mfma_f32_16x16x32_bf16(a, b, c, 0, 0, 0);
}
__device__ __forceinline__ void split4(float4 x, bf16x4& hv, bf16x4& lv) {
  hv[0] = (bf16_t)x.x; lv[0] = (bf16_t)(x.x - (float)hv[0]);
  hv[1] = (bf16_t)x.y; lv[1] = (bf16_t)(x.y - (float)hv[1]);
  hv[2] = (bf16_t)x.z; lv[2] = (bf16_t)(x.z - (float)hv[2]);
  hv[3] = (bf16_t)x.w; lv[3] = (bf16_t)(x.w - (float)hv[3]);
}

// ===========================================================================
// Prep + entr zero-init fused. Blocks [0,256): Q,K -> bf16 hi/lo planes
// [bh][l][e], V -> VT bf16 [bh][e][s]. Blocks [256,272): zero entr.
// ===========================================================================
__global__ __launch_bounds__(256) void k_prep(
    const float* __restrict__ q, const float* __restrict__ k,
    const float* __restrict__ v, bf16_t* __restrict__ ws,
    float* __restrict__ entr)
{
  const int bid = blockIdx.x;
  if (bid >= 256) {  // zero-init entr: 16 blocks * 256 thr * 4 f32 = 16384
    const int idx = (bid - 256) * 256 + threadIdx.x;
    *(float4*)(entr + (size_t)idx * 4) = make_float4(0.f, 0.f, 0.f, 0.f);
    return;
  }
  bf16_t* Qh = ws;
  bf16_t* Ql = ws + PL;
  bf16_t* Kh = ws + 2 * PL;
  bf16_t* Kl = ws + 3 * PL;
  bf16_t* VT = ws + 4 * PL;
  const int bh = bid >> 4, chunk = bid & 15;   // 64-row chunks
  const int b = bh >> 3, h = bh & 7;
  const int tid = threadIdx.x, t8 = tid >> 4, c4 = tid & 15;
  __shared__ bf16_t Vb[64][72];  // [e][l-local 64]

#pragma unroll
  for (int pass = 0; pass < 4; ++pass) {
    const int row = chunk * 64 + pass * 16 + t8;
    const size_t gin = ((size_t)(b * L + row) * H + h) * E + c4 * 4;
    const size_t gout = ((size_t)bh * L + row) * E + c4 * 4;
    float4 q4 = *(const float4*)(q + gin);
    float4 k4 = *(const float4*)(k + gin);
    float4 v4 = *(const float4*)(v + gin);
    bf16x4 hv, lv;
    split4(q4, hv, lv);
    *(bf16x4*)(Qh + gout) = hv; *(bf16x4*)(Ql + gout) = lv;
    split4(k4, hv, lv);
    *(bf16x4*)(Kh + gout) = hv; *(bf16x4*)(Kl + gout) = lv;
    const int sl = pass * 16 + t8;
    Vb[c4 * 4 + 0][sl] = (bf16_t)v4.x;
    Vb[c4 * 4 + 1][sl] = (bf16_t)v4.y;
    Vb[c4 * 4 + 2][sl] = (bf16_t)v4.z;
    Vb[c4 * 4 + 3][sl] = (bf16_t)v4.w;
  }
  __syncthreads();
#pragma unroll
  for (int pass = 0; pass < 2; ++pass) {
    const int idx = pass * 256 + tid;
    const int e = idx >> 3, ch = idx & 7;
    bf16x8 val = *(const bf16x8*)&Vb[e][ch * 8];
    *(bf16x8*)(VT + ((size_t)bh * E + e) * L + chunk * 64 + ch * 8) = val;
  }
}

// ===========================================================================
// k_sym: paired strips WITH the R0 loop/prefetch structure (R1 post-mortem:
// one-tile blocks were latency-bound; all pipes <20%). 32 strips of 32 rows.
// Block (I, bh, z): A-side = strip I (held in registers), loops over J =
// (I+it)&31; z=0 does it in [0,8), z=1 does [8,niter), niter = 17 for I<16
// else 16 (diag + gaps 1..15 from all strips, gap 16 only from I<16).
// Each unordered strip pair computed ONCE: dual QK^T gives both att(l,s)
// (direct store, rows I) and att(s,l) (mirror store via LDS transpose,
// 128B full lines, rows J). Transcendentals: 11 per element PAIR (half of
// R0's k_main). Diag tile (it==0): pair formula valid element-wise; mirror
// store and entS flush skipped. Regular cached stores (NOT nontemporal):
// R1 showed NT partial-line writes amplified WRITE_SIZE 2x and evicted att
// before k_pv. Prefetch of next J-strip issued right after the staging
// barrier so the vmcnt drain lands a full MFMA+transform phase later.
// ===========================================================================
__global__ __launch_bounds__(256, 2) void k_sym(
    const bf16_t* __restrict__ ws, float* __restrict__ attg,
    float* __restrict__ entr,
    const float* __restrict__ p_lgg, const float* __restrict__ p_ltg,
    const float* __restrict__ p_lgd, const float* __restrict__ p_ltd)
{
  const bf16_t* Qh = ws;
  const bf16_t* Ql = ws + PL;
  const bf16_t* Kh = ws + 2 * PL;
  const bf16_t* Kl = ws + 3 * PL;

  __shared__ __align__(16) bf16_t P_s[4][32][72];   // Kh,Kl,Qh,Ql J-strip
  __shared__ __align__(16) float att2f[32][36];     // a2 transpose buffer

  const int tid = threadIdx.x;
  const int w = tid >> 6, lane = tid & 63;
  const int c = lane & 15, qd = lane >> 4;
  const int lh = w & 1, sh = w >> 1;
  const int I = blockIdx.x, bh = blockIdx.y, z = blockIdx.z;
  const int niter = (I < 16) ? 17 : 16;
  const int itlo = z ? 8 : 0;
  const int ithi = z ? niter : 8;

  const float gg = fminf(fmaxf(__expf(p_lgg[0]), 1e-3f), 20.0f);
  const float tg = fminf(fmaxf(__expf(p_ltg[0]), 1e-3f), 10.0f);
  const float gd = fminf(fmaxf(__expf(p_lgd[0]), 1e-3f), 20.0f);
  const float td = fminf(fmaxf(__expf(p_ltd[0]), 1e-3f), 10.0f);
  // Folded coefficients (scores 1/8 * symmetrize 1/2 = 1/16; tanh via exp2):
  const float A1 = 0.125f * (1.0f / tg) * LOG2E;
  const float A2 = 0.125f * (1.0f / td) * LOG2E;
  const float A3 = 0.125f * gd * (1.0f / td) * LOG2E;
  const float G1 = -gg * LOG2E, G1m2 = -2.0f * G1;
  const float G2 = -gd * LOG2E, G2m2 = -2.0f * G2;

  // A-fragments: Q/K hi+lo rows I*32 + lh*16 + c, held all loop.
  bf16x8 qaf[2][2], kaf[2][2];
  {
    const size_t aro = ((size_t)bh * L + I * 32 + lh * 16 + c) * E;
#pragma unroll
    for (int ks = 0; ks < 2; ++ks) {
      qaf[ks][0] = *(const bf16x8*)(Qh + aro + ks * 32 + qd * 8);
      qaf[ks][1] = *(const bf16x8*)(Ql + aro + ks * 32 + qd * 8);
      kaf[ks][0] = *(const bf16x8*)(Kh + aro + ks * 32 + qd * 8);
      kaf[ks][1] = *(const bf16x8*)(Kl + aro + ks * 32 + qd * 8);
    }
  }

  // Staging: wave w stages plane w (32 rows x 128B = 4KB); lane covers
  // 64 contiguous bytes at row lane>>1, cols (lane&1)*32.
  const bf16_t* planep = (w == 0) ? Kh : (w == 1) ? Kl : (w == 2) ? Qh : Ql;
  const int prow = lane >> 1;
  const int pcol = (lane & 1) * 32;

  bf16x8 pf0, pf1, pf2, pf3;
  {
    const size_t off =
        ((size_t)bh * L + (size_t)((I + itlo) & 31) * 32 + prow) * E + pcol;
    pf0 = *(const bf16x8*)(planep + off);
    pf1 = *(const bf16x8*)(planep + off + 8);
    pf2 = *(const bf16x8*)(planep + off + 16);
    pf3 = *(const bf16x8*)(planep + off + 24);
  }

  float entL[4] = {0.f, 0.f, 0.f, 0.f};  // entropy rows I-strip (log2 domain)

  for (int it = itlo; it < ithi; ++it) {
    const int J = (I + it) & 31;
    const int Jn = (I + it + 1) & 31;

    __syncthreads();   // prior-iter P_s reads + att2f mirror reads done
    *(bf16x8*)&P_s[w][prow][pcol]      = pf0;
    *(bf16x8*)&P_s[w][prow][pcol + 8]  = pf1;
    *(bf16x8*)&P_s[w][prow][pcol + 16] = pf2;
    *(bf16x8*)&P_s[w][prow][pcol + 24] = pf3;
    __syncthreads();   // staged tile visible

    // prefetch it+1 NOW (drain lands at next iteration's staging write)
    {
      const size_t off = ((size_t)bh * L + (size_t)Jn * 32 + prow) * E + pcol;
      pf0 = *(const bf16x8*)(planep + off);
      pf1 = *(const bf16x8*)(planep + off + 8);
      pf2 = *(const bf16x8*)(planep + off + 16);
      pf3 = *(const bf16x8*)(planep + off + 24);
    }

    // Dual QK^T: acc1 = Q[l].K[s], acc2 = K[l].Q[s]. Term order matched so
    // the true diagonal cancels bitwise (d == 0 at l == s).
    f32x4 acc1 = {}, acc2 = {};
    const int brow = sh * 16 + c;
#pragma unroll
    for (int ks = 0; ks < 2; ++ks) {
      bf16x8 kbh = *(const bf16x8*)&P_s[0][brow][ks * 32 + qd * 8];
      bf16x8 kbl = *(const bf16x8*)&P_s[1][brow][ks * 32 + qd * 8];
      bf16x8 qbh = *(const bf16x8*)&P_s[2][brow][ks * 32 + qd * 8];
      bf16x8 qbl = *(const bf16x8*)&P_s[3][brow][ks * 32 + qd * 8];
      acc1 = mfma16(qaf[ks][0], kbh, acc1);
      acc1 = mfma16(qaf[ks][0], kbl, acc1);
      acc1 = mfma16(qaf[ks][1], kbh, acc1);
      acc2 = mfma16(kaf[ks][0], qbh, acc2);
      acc2 = mfma16(kaf[ks][1], qbh, acc2);
      acc2 = mfma16(kaf[ks][0], qbl, acc2);
    }

    // Pair transform: element (l = I*32+lh*16+qd*4+r, s = J*32+sh*16+c).
    // Exactly one of a1=att(l,s), a2=att(s,l) is nonzero -> one shared log.
    float entS = 0.f;
    float* arow = attg + ((size_t)bh * L + I * 32 + lh * 16 + qd * 4) * L +
                  (size_t)J * 32 + sh * 16;
    f32x4 a2v;
#pragma unroll
    for (int r = 0; r < 4; ++r) {
      const float u = acc1[r] + acc2[r];    // 16*S_sym
      const float d = acc1[r] - acc2[r];    // 16*A_anti
      const float r1 = rcp_fast(exp2_fast(u * A1) + 1.f);
      const float gate = rcp_fast(1.f + exp2_fast(fmaf(r1, G1m2, G1)));
      const float r2 = rcp_fast(exp2_fast(d * A2) + 1.f);
      const float dir = rcp_fast(1.f + exp2_fast(fmaf(r2, G2m2, G2)));
      const float t = fmaf(rcp_fast(exp2_fast(d * A3) + 1.f), -2.f, 1.f);
      const float gdp = gate * dir;
      const float a1 = fmaxf(t, 0.f) * gdp;             // att(l,s)
      const float a2 = fmaxf(-t, 0.f) * (gate - gdp);   // att(s,l)
      const float la = log2_fast(fmaxf(a1 + a2, 1e-8f));
      entL[r] -= a1 * la;
      entS -= a2 * la;
      arow[(size_t)r * L + c] = a1;                     // cached store
      a2v[r] = a2;
    }
    *(f32x4*)&att2f[sh * 16 + c][lh * 16 + qd * 4] = a2v;
    __syncthreads();   // att2f visible block-wide

    if (it != 0) {
      // Mirror tile: att rows J*32+mr, cols I*32..+32 -> full 128B lines.
      const int mr = tid >> 3, mc = (tid & 7) * 4;
      float* orow =
          attg + ((size_t)bh * L + (size_t)J * 32 + mr) * L + (size_t)I * 32 + mc;
      *(f32x4*)orow = *(const f32x4*)&att2f[mr][mc];

      // entS flush: reduce over qd (the 16 l-rows this wave covers).
      float e = entS;
      e += __shfl_xor(e, 16);
      e += __shfl_xor(e, 32);
      if (lane < 16)
        atomicAdd(entr + (size_t)bh * L + (size_t)J * 32 + sh * 16 + c, e * LN2);
    }
  }

  // entL flush: reduce over c (s-cols), accumulated across all iterations.
#pragma unroll
  for (int r = 0; r < 4; ++r) {
    float e = entL[r];
    e += __shfl_xor(e, 1);
    e += __shfl_xor(e, 2);
    e += __shfl_xor(e, 4);
    e += __shfl_xor(e, 8);
    if (c == 0)
      atomicAdd(entr + (size_t)bh * L + I * 32 + lh * 16 + qd * 4 + r, e * LN2);
  }
}

// ===========================================================================
// k_pv v2: Vout = att @ V. R1's v1 had all 4 waves re-reading the same att
// rows (4x redundant cache reads of NT-evicted data). v2 stages the 32x64
// f32 att tile through LDS ONCE per block (fully line-coalesced 256B-row
// loads, register double-buffer), converts to bf16, feeds all 4 waves.
// grid (32 lt, 16 bh), 256 thr; wave w: l-half w&1, e-half w>>1.
// Plain stores, no atomics, no zero-init.
// ===========================================================================
__global__ __launch_bounds__(256, 2) void k_pv(
    const bf16_t* __restrict__ ws, const float* __restrict__ attg,
    float* __restrict__ Vout)
{
  const bf16_t* VT = ws + 4 * PL;
  __shared__ __align__(16) bf16_t att_s[32][72];

  const int tid = threadIdx.x;
  const int w = tid >> 6, lane = tid & 63;
  const int c = lane & 15, qd = lane >> 4;
  const int mh = w & 1, eh = w >> 1;
  const int lt = blockIdx.x, bh = blockIdx.y;
  const int b = bh >> 3, h = bh & 7;
  const int l0 = lt * 32;

  // staging: row = tid>>3 (32 rows), cols (tid&7)*8 (8 f32 = 32B/thread)
  const int srow = tid >> 3, scol = (tid & 7) * 8;
  const float* abase = attg + ((size_t)bh * L + l0 + srow) * L + scol;

  f32x4 pa = *(const f32x4*)(abase);
  f32x4 pb = *(const f32x4*)(abase + 4);

  const bf16_t* vbase = VT + ((size_t)bh * E + eh * 32) * L;

  f32x4 acc[2] = {};
  for (int st = 0; st < 16; ++st) {
    __syncthreads();   // prior MFMA reads of att_s done
    {
      bf16x8 af;
      af[0] = (bf16_t)pa[0]; af[1] = (bf16_t)pa[1];
      af[2] = (bf16_t)pa[2]; af[3] = (bf16_t)pa[3];
      af[4] = (bf16_t)pb[0]; af[5] = (bf16_t)pb[1];
      af[6] = (bf16_t)pb[2]; af[7] = (bf16_t)pb[3];
      *(bf16x8*)&att_s[srow][scol] = af;
    }
    __syncthreads();   // staged tile visible
    {
      const int stn = (st + 1) & 15;   // wrap: last prefetch harmless
      pa = *(const f32x4*)(abase + stn * 64);
      pb = *(const f32x4*)(abase + stn * 64 + 4);
    }
#pragma unroll
    for (int ks = 0; ks < 2; ++ks) {
      bf16x8 av = *(const bf16x8*)&att_s[mh * 16 + c][ks * 32 + qd * 8];
#pragma unroll
      for (int n = 0; n < 2; ++n) {
        bf16x8 bv = *(const bf16x8*)(vbase + (size_t)(n * 16 + c) * L +
                                     st * 64 + ks * 32 + qd * 8);
        acc[n] = mfma16(av, bv, acc[n]);
      }
    }
  }
#pragma unroll
  for (int n = 0; n < 2; ++n)
#pragma unroll
    for (int r = 0; r < 4; ++r)
      Vout[((size_t)(b * L + l0 + mh * 16 + qd * 4 + r) * H + h) * E +
           eh * 32 + n * 16 + c] = acc[n][r];
}

// ===========================================================================
// Fallback (R2 kernel) if ws_size is too small for the planes.
// ===========================================================================
__device__ __forceinline__ float tanh_fast(float x) {
  return 1.0f - 2.0f * rcp_fast(__expf(2.0f * x) + 1.0f);
}
__device__ __forceinline__ float sigm_fast(float x) {
  return rcp_fast(1.0f + __expf(-x));
}
__device__ __forceinline__ void split_store(bf16_t* hi, bf16_t* lo, float4 x) {
  bf16x4 hv, lv;
  split4(x, hv, lv);
  *(bf16x4*)hi = hv;
  *(bf16x4*)lo = lv;
}

__global__ __launch_bounds__(128, 1) void fused_attn(
    const float* __restrict__ q, const float* __restrict__ kk,
    const float* __restrict__ v,
    float* __restrict__ Vout, float* __restrict__ attg, float* __restrict__ entr,
    const float* __restrict__ p_lgg, const float* __restrict__ p_ltg,
    const float* __restrict__ p_lgd, const float* __restrict__ p_ltd)
{
  constexpr int TM = 32;
  __shared__ bf16_t Qa_hi[TM][72], Qa_lo[TM][72];
  __shared__ bf16_t Ka_hi[TM][72], Ka_lo[TM][72];
  __shared__ bf16_t KQ_hi[64][72], KQ_lo[64][72];
  __shared__ bf16_t Vts[64][72];
  __shared__ float  T2ex[2][64][17];
  __shared__ bf16_t attLs[2][16][72];

  const int tid = threadIdx.x;
  const int w = tid >> 6;
  const int lane = tid & 63;
  const int c = lane & 15;
  const int qd = lane >> 4;
  const int t8 = tid >> 4;
  const int c4 = tid & 15;
  const int lt = blockIdx.x;
  const int bh = blockIdx.y;
  const int b = bh >> 3, h = bh & 7;
  const int l0 = lt * TM;

  const float gg = fminf(fmaxf(__expf(p_lgg[0]), 1e-3f), 20.0f);
  const float tg = fminf(fmaxf(__expf(p_ltg[0]), 1e-3f), 10.0f);
  const float gd = fminf(fmaxf(__expf(p_lgd[0]), 1e-3f), 20.0f);
  const float td = fminf(fmaxf(__expf(p_ltd[0]), 1e-3f), 10.0f);
  const float inv_tg = 1.0f / tg;
  const float inv_td = 1.0f / td;
  const float gd_inv_td = gd * inv_td;

  const float* qlbase = q  + ((size_t)(b * L + l0) * H + h) * E;
  const float* qsbase = q  + ((size_t)b * L * H + h) * E;
  const float* kbase  = kk + ((size_t)b * L * H + h) * E;
  const float* vbase  = v  + ((size_t)b * L * H + h) * E;

#pragma unroll
  for (int i = 0; i < 4; ++i) {
    int r = t8 + 8 * i;
    float4 qa = *(const float4*)(qlbase + (size_t)r * HE + c4 * 4);
    float4 ka = *(const float4*)(kbase + (size_t)(l0 + r) * HE + c4 * 4);
    split_store(&Qa_hi[r][c4 * 4], &Qa_lo[r][c4 * 4], qa);
    split_store(&Ka_hi[r][c4 * 4], &Ka_lo[r][c4 * 4], ka);
  }

  float4 kpre[8], qpre[8];
  float vpre[32];
#pragma unroll
  for (int i = 0; i < 8; ++i)
    kpre[i] = *(const float4*)(kbase + (size_t)(t8 + 8 * i) * HE + c4 * 4);
#pragma unroll
  for (int i = 0; i < 8; ++i)
    qpre[i] = *(const float4*)(qsbase + (size_t)(t8 + 8 * i) * HE + c4 * 4);
#pragma unroll
  for (int j = 0; j < 32; ++j)
    vpre[j] = vbase[(size_t)(w * 32 + j) * HE + lane];

  __syncthreads();

  bf16x8 qaf[2][2], kaf[2][2];
#pragma unroll
  for (int ks = 0; ks < 2; ++ks) {
    qaf[ks][0] = *(const bf16x8*)&Qa_hi[w * 16 + c][ks * 32 + qd * 8];
    qaf[ks][1] = *(const bf16x8*)&Qa_lo[w * 16 + c][ks * 32 + qd * 8];
    kaf[ks][0] = *(const bf16x8*)&Ka_hi[w * 16 + c][ks * 32 + qd * 8];
    kaf[ks][1] = *(const bf16x8*)&Ka_lo[w * 16 + c][ks * 32 + qd * 8];
  }

  f32x4 accv[4] = {};
  float ent[4] = {0.f, 0.f, 0.f, 0.f};
  const int gl_base = l0 + w * 16 + qd * 4;

  for (int it = 0; it < 16; ++it) {
    const int s0 = it * 64;
    const int snext = ((it + 1) & 15) * 64;

    __syncthreads();
#pragma unroll
    for (int i = 0; i < 8; ++i) {
      int r = t8 + 8 * i;
      split_store(&KQ_hi[r][c4 * 4], &KQ_lo[r][c4 * 4], kpre[i]);
    }
#pragma unroll
    for (int j = 0; j < 16; ++j) {
      bf16x2 p;
      p[0] = (bf16_t)vpre[2 * j];
      p[1] = (bf16_t)vpre[2 * j + 1];
      *(bf16x2*)&Vts[lane][w * 32 + 2 * j] = p;
    }
    __syncthreads();

#pragma unroll
    for (int i = 0; i < 8; ++i)
      kpre[i] = *(const float4*)(kbase + (size_t)(snext + t8 + 8 * i) * HE + c4 * 4);
#pragma unroll
    for (int j = 0; j < 32; ++j)
      vpre[j] = vbase[(size_t)(snext + w * 32 + j) * HE + lane];

    f32x4 acc1[4] = {};
#pragma unroll
    for (int nt = 0; nt < 4; ++nt) {
#pragma unroll
      for (int ks = 0; ks < 2; ++ks) {
        bf16x8 bhv = *(const bf16x8*)&KQ_hi[nt * 16 + c][ks * 32 + qd * 8];
        bf16x8 blv = *(const bf16x8*)&KQ_lo[nt * 16 + c][ks * 32 + qd * 8];
        acc1[nt] = mfma16(qaf[ks][0], bhv, acc1[nt]);
        acc1[nt] = mfma16(qaf[ks][0], blv, acc1[nt]);
        acc1[nt] = mfma16(qaf[ks][1], bhv, acc1[nt]);
      }
    }
    __syncthreads();

#pragma unroll
    for (int i = 0; i < 8; ++i) {
      int r = t8 + 8 * i;
      split_store(&KQ_hi[r][c4 * 4], &KQ_lo[r][c4 * 4], qpre[i]);
    }
    __syncthreads();

#pragma unroll
    for (int i = 0; i < 8; ++i)
      qpre[i] = *(const float4*)(qsbase + (size_t)(snext + t8 + 8 * i) * HE + c4 * 4);

    f32x4 acc2[4] = {};
#pragma unroll
    for (int mt = 0; mt < 4; ++mt) {
#pragma unroll
      for (int ks = 0; ks < 2; ++ks) {
        bf16x8 ahv = *(const bf16x8*)&KQ_hi[mt * 16 + c][ks * 32 + qd * 8];
        bf16x8 alv = *(const bf16x8*)&KQ_lo[mt * 16 + c][ks * 32 + qd * 8];
        acc2[mt] = mfma16(ahv, kaf[ks][0], acc2[mt]);
        acc2[mt] = mfma16(ahv, kaf[ks][1], acc2[mt]);
        acc2[mt] = mfma16(alv, kaf[ks][0], acc2[mt]);
      }
    }

#pragma unroll
    for (int mt = 0; mt < 4; ++mt)
#pragma unroll
      for (int r = 0; r < 4; ++r)
        T2ex[w][mt * 16 + qd * 4 + r][c] = acc2[mt][r];
    __syncthreads();

    float* attrow0 = attg + ((size_t)bh * L + gl_base) * L + s0;
#pragma unroll
    for (int nt = 0; nt < 4; ++nt) {
#pragma unroll
      for (int r = 0; r < 4; ++r) {
        float x = 0.125f * acc1[nt][r];
        float y = 0.125f * T2ex[w][nt * 16 + c][qd * 4 + r];
        float Ss = 0.5f * (x + y);
        float Aa = 0.5f * (x - y);
        float gate = sigm_fast(gg * tanh_fast(Ss * inv_tg));
        float dir  = sigm_fast(gd * tanh_fast(Aa * inv_td));
        float t    = tanh_fast(Aa * gd_inv_td);
        float a = fmaxf(t, 0.0f) * gate * dir;
        ent[r] -= a * __logf(fmaxf(a, 1e-8f));
        attrow0[(size_t)r * L + nt * 16 + c] = a;
        attLs[w][qd * 4 + r][nt * 16 + c] = (bf16_t)a;
      }
    }
    __syncthreads();

#pragma unroll
    for (int ks = 0; ks < 2; ++ks) {
      bf16x8 af = *(const bf16x8*)&attLs[w][c][ks * 32 + qd * 8];
#pragma unroll
      for (int ne = 0; ne < 4; ++ne) {
        bf16x8 bfv = *(const bf16x8*)&Vts[ne * 16 + c][ks * 32 + qd * 8];
        accv[ne] = mfma16(af, bfv, accv[ne]);
      }
    }
  }

#pragma unroll
  for (int r = 0; r < 4; ++r) {
    float* vb = Vout + ((size_t)(b * L + gl_base + r) * H + h) * E;
#pragma unroll
    for (int ne = 0; ne < 4; ++ne) vb[ne * 16 + c] = accv[ne][r];
    float e4 = ent[r];
    e4 += __shfl_xor(e4, 1);
    e4 += __shfl_xor(e4, 2);
    e4 += __shfl_xor(e4, 4);
    e4 += __shfl_xor(e4, 8);
    if (c == 0) entr[(size_t)bh * L + gl_base + r] = e4;
  }
}

}  // namespace

extern "C" void kernel_launch(void* const* d_in, const int* in_sizes, int n_in,
                              void* d_out, int out_size, void* d_ws, size_t ws_size,
                              hipStream_t stream) {
  const float* q = (const float*)d_in[0];
  const float* k = (const float*)d_in[1];
  const float* v = (const float*)d_in[2];
  const float* p_lgg = (const float*)d_in[7];
  const float* p_ltg = (const float*)d_in[8];
  const float* p_lgd = (const float*)d_in[9];
  const float* p_ltd = (const float*)d_in[10];

  float* Vout = (float*)d_out;          // (B,L,H,E)   1,048,576
  float* att  = Vout + 1048576;         // (B,H,L,S)  16,777,216
  float* entr = att + 16777216;         // (B,H,L)        16,384

  const size_t need = 5 * PL * sizeof(bf16_t);  // 10,485,760 B
  if (ws_size >= need) {
    bf16_t* ws = (bf16_t*)d_ws;
    k_prep<<<dim3(272), 256, 0, stream>>>(q, k, v, ws, entr);
    k_sym<<<dim3(32, 16, 2), 256, 0, stream>>>(
        ws, att, entr, p_lgg, p_ltg, p_lgd, p_ltd);
    k_pv<<<dim3(32, 16), 256, 0, stream>>>(ws, att, Vout);
  } else {
    fused_attn<<<dim3(32, 16), 128, 0, stream>>>(
        q, k, v, Vout, att, entr, p_lgg, p_ltg, p_lgd, p_ltd);
  }
}